// Round 1
// 126.333 us; speedup vs baseline: 1.0550x; 1.0550x over previous
//
#include <hip/hip_runtime.h>

// VQ: x (16,64,64,64) f32, codebook e (64,1024) f32. N=65536, D=64, K=1024.
//
// R7: attack vq_main's latency-boundedness (18% occupancy, 24us of dual-idle)
//  - K-split: block = 64 positions, 4 waves = (pg 0/1) x (kh 0/1); each wave
//    2 M-tiles over 32 k-tiles. Grid 512 -> 1024 blocks (4 blocks/CU).
//    Cross-kh top-2 merge via tiny LDS.
//  - An dropped from the tracked score: constant per position, cancels in
//    both argmin and the s2-s1 margin gap. Track m = x.e - 0.5*c2 (argMAX)
//    by initializing the MFMA accumulator with precomputed -0.5*c2[k]:
//    epilogue is 5 VALU ops/element (min/max second-best trick), no fma/add.
//    Margin certificate: score gap = 2*(m1-m2), so fallback iff
//    m1-m2 <= MARGIN/2. vq_norms kernel DELETED (fallback computes Ap).
//  - prep_c2 fused into prep_e; fallback register-caches x (was 4x reload)
//    and runs on 512 blocks.
//  Certification unchanged: split-bf16 3-term MFMA approx, |approx - np| per
//  score bounded as before (An shift is common-mode); ambiguous positions are
//  re-resolved by the bit-exact numpy-fp32 scan and overwritten.

#define D 64
#define K 1024
#define NPOS 65536
#define HW 4096
#define XSTRIDE 262144  // D*HW
#define MARGIN 1.0e-3f

typedef float vfloat4 __attribute__((ext_vector_type(4)));
typedef short short8  __attribute__((ext_vector_type(8)));

static __device__ __forceinline__ unsigned short bf16_rne(float f) {
    unsigned u = __float_as_uint(f);
    u += 0x7FFFu + ((u >> 16) & 1u);
    return (unsigned short)(u >> 16);
}
static __device__ __forceinline__ float bf16_to_f32(unsigned short h) {
    return __uint_as_float(((unsigned)h) << 16);
}

// ---- prep (fused): codebook -> bf16 split B-fragments + c2n = -0.5*sum(e^2)
// frag layout: ebf[tile][s][split][lane][j], lane=q*16+n, value =
// split(e[d][k]), d=s*32+q*8+j, k=tile*16+n. Lane l reads 16B at l*16.
// c2n[k] = -0.5 * (sequential-d sum of rounded squares)  [exact *0.5 scale,
// so fallback's c2[k] = -2*c2n[k] is bit-identical to the old prep_c2].
__global__ void vq_prep(const float* __restrict__ e,
                        unsigned short* __restrict__ ebf,
                        float* __restrict__ c2n,
                        int* __restrict__ wl_count) {
    const int tile = blockIdx.x;               // 0..63
    const int t = threadIdx.x;
    if (tile == 0 && t == 0) *wl_count = 0;    // ws re-poisoned every launch
    const int n = t & 15;
    const int dg = t >> 4;                     // 0..15
#pragma unroll
    for (int i = 0; i < 4; ++i) {
        const int d = dg * 4 + i;
        const float v = e[d * K + tile * 16 + n];
        const unsigned short hh = bf16_rne(v);
        const float rem = v - bf16_to_f32(hh);     // exact (Sterbenz)
        const unsigned short hl = bf16_rne(rem);
        const int s = d >> 5, q = (d >> 3) & 3, j = d & 7;
        const int lanei = q * 16 + n;
        ebf[(((tile * 2 + s) * 2 + 0) * 64 + lanei) * 8 + j] = hh;
        ebf[(((tile * 2 + s) * 2 + 1) * 64 + lanei) * 8 + j] = hl;
    }
    if (t < 16) {
        const int k = tile * 16 + t;
        float s = 0.f;
#pragma unroll
        for (int d = 0; d < D; ++d) {
            const float v = e[d * K + k];
            s = s + __fmul_rn(v, v);
        }
        c2n[k] = -0.5f * s;
    }
}

// ---- main: 1024 blocks x 256; block = 64 positions; wave = (pg, kh) -------
__global__ __launch_bounds__(256, 4)
void vq_main(const float* __restrict__ x, const float* __restrict__ e,
             const unsigned short* __restrict__ ebf,
             const float* __restrict__ c2n,
             float* __restrict__ out, int* __restrict__ wl_count,
             int* __restrict__ wl) {
    __shared__ int   bk_lds[64];
    __shared__ float ls1[2][32];
    __shared__ float ls2[2][32];
    __shared__ int   lk1[2][32];
    const int t = threadIdx.x;
    const int lane = t & 63;
    const int w = t >> 6;
    const int pg = w & 1;                      // position group (32 each)
    const int kh = w >> 1;                     // k-half (32 tiles each)
    const int p0 = blockIdx.x * 64;
    const int b = p0 >> 12;
    const int sp0 = p0 & (HW - 1);
    const int n = lane & 15;                   // A-row m / B-col n / C col
    const int q = lane >> 4;                   // k-quad / C row group

    // A-frags (registers): xh/xl for 2 M-tiles x 2 K-steps
    short8 ah[2][2], al[2][2];
#pragma unroll
    for (int mt = 0; mt < 2; ++mt) {
        const int spc = sp0 + pg * 32 + mt * 16 + n;
#pragma unroll
        for (int s = 0; s < 2; ++s) {
            short8 fh, fl_;
#pragma unroll
            for (int j = 0; j < 8; ++j) {
                const int d = s * 32 + q * 8 + j;      // A[m=n][k=q*8+j]
                const float v = x[(size_t)b * XSTRIDE + (size_t)d * HW + spc];
                const unsigned short h = bf16_rne(v);
                fh[j] = (short)h;
                fl_[j] = (short)bf16_rne(v - bf16_to_f32(h));
            }
            ah[mt][s] = fh; al[mt][s] = fl_;
        }
    }

    const short8* ebv = (const short8*)ebf;
    float s1[2][4], s2[2][4]; int t1[2][4];
#pragma unroll
    for (int mt = 0; mt < 2; ++mt)
#pragma unroll
        for (int r = 0; r < 4; ++r) { s1[mt][r] = -3.4e38f; s2[mt][r] = -3.4e38f; t1[mt][r] = 0; }

    // software-pipelined loop over this wave's 32 k-tiles (no barriers)
    const int tbase = kh * 32;
    short8 bh0 = ebv[((tbase * 2 + 0) * 2 + 0) * 64 + lane];
    short8 bl0 = ebv[((tbase * 2 + 0) * 2 + 1) * 64 + lane];
    short8 bh1 = ebv[((tbase * 2 + 1) * 2 + 0) * 64 + lane];
    short8 bl1 = ebv[((tbase * 2 + 1) * 2 + 1) * 64 + lane];
    float c2v = c2n[tbase * 16 + n];
    for (int tt = 0; tt < 32; ++tt) {
        const int tile = tbase + tt;
        short8 nbh0, nbl0, nbh1, nbl1; float nc2;
        if (tt < 31) {                          // prefetch next tile's frags
            const int tn = tile + 1;
            nbh0 = ebv[((tn * 2 + 0) * 2 + 0) * 64 + lane];
            nbl0 = ebv[((tn * 2 + 0) * 2 + 1) * 64 + lane];
            nbh1 = ebv[((tn * 2 + 1) * 2 + 0) * 64 + lane];
            nbl1 = ebv[((tn * 2 + 1) * 2 + 1) * 64 + lane];
            nc2  = c2n[tn * 16 + n];
        }
#pragma unroll
        for (int mt = 0; mt < 2; ++mt) {
            vfloat4 acc = {c2v, c2v, c2v, c2v};    // m = x.e - 0.5*c2
            acc = __builtin_amdgcn_mfma_f32_16x16x32_bf16(ah[mt][0], bh0, acc, 0, 0, 0);
            acc = __builtin_amdgcn_mfma_f32_16x16x32_bf16(ah[mt][1], bh1, acc, 0, 0, 0);
            acc = __builtin_amdgcn_mfma_f32_16x16x32_bf16(al[mt][0], bh0, acc, 0, 0, 0);
            acc = __builtin_amdgcn_mfma_f32_16x16x32_bf16(al[mt][1], bh1, acc, 0, 0, 0);
            acc = __builtin_amdgcn_mfma_f32_16x16x32_bf16(ah[mt][0], bl0, acc, 0, 0, 0);
            acc = __builtin_amdgcn_mfma_f32_16x16x32_bf16(ah[mt][1], bl1, acc, 0, 0, 0);
#pragma unroll
            for (int r = 0; r < 4; ++r) {      // C/D: row=q*4+r, col=n; argMAX
                const float m = acc[r];
                const bool gt = m > s1[mt][r];
                s2[mt][r] = fmaxf(s2[mt][r], fminf(m, s1[mt][r]));
                s1[mt][r] = gt ? m : s1[mt][r];
                t1[mt][r] = gt ? tile : t1[mt][r];
            }
        }
        if (tt < 31) { bh0 = nbh0; bl0 = nbl0; bh1 = nbh1; bl1 = nbl1; c2v = nc2; }
    }

    // merge top-2 across the 16 code-columns (lanes within a q-group)
#pragma unroll
    for (int mt = 0; mt < 2; ++mt)
#pragma unroll
        for (int r = 0; r < 4; ++r) {
            float a1 = s1[mt][r], a2 = s2[mt][r];
            int ak = t1[mt][r] * 16 + n;
#pragma unroll
            for (int m = 1; m < 16; m <<= 1) {
                const float o1 = __shfl_xor(a1, m, 64);
                const float o2 = __shfl_xor(a2, m, 64);
                const int   ok = __shfl_xor(ak, m, 64);
                const bool take = (o1 > a1) || (o1 == a1 && ok < ak);
                const float loser = take ? a1 : o1;
                a1 = take ? o1 : a1;
                ak = take ? ok : ak;
                a2 = fmaxf(fmaxf(a2, o2), loser);
            }
            s1[mt][r] = a1; s2[mt][r] = a2; t1[mt][r] = ak;  // ak is code idx
            if (kh == 1 && n == 0) {
                const int pos32 = mt * 16 + q * 4 + r;
                ls1[pg][pos32] = a1; ls2[pg][pos32] = a2; lk1[pg][pos32] = ak;
            }
        }
    __syncthreads();

    // kh==0 combines both K-halves, certifies, pushes ambiguous to worklist
    if (kh == 0 && n == 0) {
#pragma unroll
        for (int mt = 0; mt < 2; ++mt)
#pragma unroll
            for (int r = 0; r < 4; ++r) {
                const int pos32 = mt * 16 + q * 4 + r;
                const float a1 = s1[mt][r], a2 = s2[mt][r];
                const int   ak = t1[mt][r];
                const float b1 = ls1[pg][pos32], b2 = ls2[pg][pos32];
                const int   bk2 = lk1[pg][pos32];
                const bool take = (b1 > a1) || (b1 == a1 && bk2 < ak);
                const float w1 = take ? b1 : a1;
                const int   wk = take ? bk2 : ak;
                const float w2 = fmaxf(fminf(a1, b1), fmaxf(a2, b2));
                bk_lds[pg * 32 + pos32] = wk;
                if (w1 - w2 <= 0.5f * MARGIN) {   // score gap = 2*(m1-m2)
                    const int idx = atomicAdd(wl_count, 1);
                    wl[idx] = p0 + pg * 32 + pos32;
                }
            }
    }
    __syncthreads();

    // write all 64 positions x 64 channels (fallback overwrites ambiguous)
    const int pl = t & 63;
    const int cg = t >> 6;
    const int bk = bk_lds[pl];
    const int sp = sp0 + pl;
    const float* xb = x + (size_t)b * XSTRIDE + sp;
    float* ob = out + (size_t)b * XSTRIDE + sp;
#pragma unroll
    for (int i = 0; i < 16; ++i) {
        const int c = cg * 16 + i;
        const float xq = xb[(size_t)c * HW];
        const float qv = e[c * K + bk];
        ob[(size_t)c * HW] = xq + (qv - xq);   // np STE: fl(x + fl(q-x))
    }
}

// ---- fallback: bit-exact np scan for ambiguous positions -----------------
__global__ __launch_bounds__(256, 2)
void vq_fallback(const float* __restrict__ x, const float* __restrict__ e,
                 const float* __restrict__ c2n,
                 const int* __restrict__ wl_count, const int* __restrict__ wl,
                 float* __restrict__ out) {
    __shared__ float rs[256];
    __shared__ int   rk[256];
    const int t = threadIdx.x;
    const int count = *wl_count;
    for (int i = blockIdx.x; i < count; i += gridDim.x) {
        const int pos = wl[i];
        const int b = pos >> 12, sp = pos & (HW - 1);
        float xv[D];                            // register-cache x (was 4x reload)
#pragma unroll
        for (int d = 0; d < D; ++d)
            xv[d] = x[(size_t)b * XSTRIDE + (size_t)d * HW + sp];
        // Ap = np.sum(x**2) in numpy pairwise-8 order (bit-identical to old
        // vq_norms)
        float r8[8];
#pragma unroll
        for (int i0 = 0; i0 < 8; ++i0) r8[i0] = __fmul_rn(xv[i0], xv[i0]);
#pragma unroll
        for (int j = 1; j < 8; ++j)
#pragma unroll
            for (int i0 = 0; i0 < 8; ++i0)
                r8[i0] = r8[i0] + __fmul_rn(xv[8 * j + i0], xv[8 * j + i0]);
        const float Ap = ((r8[0] + r8[1]) + (r8[2] + r8[3])) + ((r8[4] + r8[5]) + (r8[6] + r8[7]));
        float bs = 3.4e38f; int bk = 0x7fffffff;
#pragma unroll
        for (int j = 0; j < 4; ++j) {
            const int k = t + 256 * j;         // ascending k per thread
            float acc = 0.f;
#pragma unroll
            for (int d = 0; d < D; ++d)        // sequential-k FMA chain (np)
                acc = __builtin_fmaf(xv[d], e[d * K + k], acc);
            const float c2k = -2.0f * c2n[k];  // exact pow2 scale = old c2[k]
            const float sc = __builtin_fmaf(-2.f, acc, Ap) + c2k;
            if (sc < bs || (sc == bs && k < bk)) { bs = sc; bk = k; }
        }
        rs[t] = bs; rk[t] = bk;
        __syncthreads();
        for (int off = 128; off > 0; off >>= 1) {
            if (t < off) {
                const float so = rs[t + off]; const int ko = rk[t + off];
                if (so < rs[t] || (so == rs[t] && ko < rk[t])) { rs[t] = so; rk[t] = ko; }
            }
            __syncthreads();
        }
        const int kb = rk[0];
        if (t < 64) {
            const float xq = x[(size_t)b * XSTRIDE + (size_t)t * HW + sp];
            const float qv = e[t * K + kb];
            out[(size_t)b * XSTRIDE + (size_t)t * HW + sp] = xq + (qv - xq);
        }
        __syncthreads();
    }
}

extern "C" void kernel_launch(void* const* d_in, const int* in_sizes, int n_in,
                              void* d_out, int out_size, void* d_ws, size_t ws_size,
                              hipStream_t stream) {
    const float* x = (const float*)d_in[0];
    const float* e = (const float*)d_in[1];
    float* out = (float*)d_out;

    char* ws = (char*)d_ws;                          // ~517 KB used
    unsigned short* ebf = (unsigned short*)ws;       // 256 KB B-fragments
    float* c2n = (float*)(ws + 262144);              // 4 KB  (-0.5*sum e^2)
    int* wl_count = (int*)(ws + 266240);             // 16 B
    int* wl = (int*)(ws + 266256);                   // 256 KB worklist

    vq_prep<<<64, 256, 0, stream>>>(e, ebf, c2n, wl_count);
    vq_main<<<NPOS / 64, 256, 0, stream>>>(x, e, ebf, c2n, out, wl_count, wl);
    vq_fallback<<<512, 256, 0, stream>>>(x, e, c2n, wl_count, wl, out);
}